// Round 5
// baseline (149.907 us; speedup 1.0000x reference)
//
#include <hip/hip_runtime.h>
#include <math.h>

// ---------------- problem constants ----------------
#define KK     9
#define NCLS   13
#define NANC   5
#define NBB    128
#define NHH    26
#define NWW    26
#define NTT    50
#define LL     21
#define CHC    32
#define NPIX   676
#define NANCHT 3380
#define NCELLT 432640
#define GTS    20     // floats per target in fp32 exact-path table
#define GTH    24     // halves per target in fp16 cull table (48 B)
#define MWPB   106    // mask words per batch
#define HALFSPLIT 1792 // slot0 covers [0,1792), slot1 = +1792
#define NBLK   7      // grid.x for confmask (7*256 = 1792)

// derived float constants
#define LOG2E_F   1.4426950408889634f
#define K1C       2.8853900817779268f   // SHARP*log2e
#define K2C       0.036067376022224085f // K1C/TH
#define SXW       24.615384615384617f   // 640/26
#define SYH       18.461538461538463f   // 480/26
#define THRESH_S  43.500902934225507f   // 9 + SIL*9*(e^2-1)
#define CULL_H    400.0f                // conservative fp16 cull (true cut 288.25 + worst-case fp16 err)
#define CONF_T_SCALE 0.017390849194407297f
#define OBJ_W     5.0f
#define EPOCH_PRETRAIN 15
#define BIGV      6.0e18f

typedef _Float16 h2 __attribute__((ext_vector_type(2)));
typedef int      i4 __attribute__((ext_vector_type(4)));

static __device__ __forceinline__ float fast_exp2(float x){ return __builtin_amdgcn_exp2f(x); }
static __device__ __forceinline__ float fast_sqrt(float x){ return __builtin_amdgcn_sqrtf(x); }
static __device__ __forceinline__ float sigmoidf_(float x){
  return 1.0f/(1.0f + fast_exp2(-LOG2E_F*x));
}
static __device__ __forceinline__ h2 bch2(int v){ return __builtin_bit_cast(h2, v); }
static __device__ __forceinline__ _Float16 hmin(_Float16 a, _Float16 b){ return a < b ? a : b; }

__constant__ float c_anch[10] = {1.482f,2.2412f,2.0501f,3.1265f,2.3946f,4.6891f,
                                 3.1018f,3.991f,3.4879f,5.8851f};

// ws layout (bytes):
//   [0,4096)         : bc_part  double[NBB][4]
//   [4096,11264)     : partials double[NBLK*NBB]
//   [11264,523264)   : gts_neg  float[NBB*NTT*GTS]   fp32 NEGATED px corners [x0..x8,BIG,y0..y8,BIG]
//   [523264,523776)  : nvalid   int[NBB]
//   [523776,578048)  : maskw    u32[NBB*MWPB]
//   [578048,885248)  : gth      _Float16[NBB*NTT*GTH] fp16 NEGATED px corners
//                        per t: [x0..x7 | y0..y7 | x8,y8 | 6 pad halves]

// ---------------- phase 0: prep ----------------
__global__ __launch_bounds__(64) void prep_kernel(const float* __restrict__ tgt,
                                                  float* __restrict__ gts_neg,
                                                  _Float16* __restrict__ gth,
                                                  int* __restrict__ nvalid){
  int b = blockIdx.x;
  int t = threadIdx.x;
  const float* trow = tgt + (size_t)b*NTT*LL;
  float v1 = (t < NTT) ? trow[t*LL + 1] : 0.0f;
  unsigned long long mk = __ballot(t < NTT && v1 != 0.0f);
  int firstInvalid = __ffsll(~mk) - 1;
  if (t == 0) nvalid[b] = firstInvalid;
  for (int idx = t; idx < NTT*GTS; idx += 64){
    int tt = idx / GTS;
    int c  = idx - tt*GTS;
    float v;
    if (c == 9 || c == 19)      v = BIGV;
    else if (c < 9)             v = -(trow[tt*LL + 1 + 2*c] * 640.0f);
    else                        v = -(trow[tt*LL + 2 + 2*(c-10)] * 480.0f);
    gts_neg[(size_t)b*NTT*GTS + idx] = v;
  }
  for (int idx = t; idx < NTT*GTH; idx += 64){
    int tt = idx / GTH;
    int c  = idx - tt*GTH;
    float v = 0.0f;
    if (c < 8)        v = -(trow[tt*LL + 1 + 2*c] * 640.0f);      // x0..x7
    else if (c < 16)  v = -(trow[tt*LL + 2 + 2*(c-8)] * 480.0f);  // y0..y7
    else if (c == 16) v = -(trow[tt*LL + 1 + 16] * 640.0f);       // x8
    else if (c == 17) v = -(trow[tt*LL + 2 + 16] * 480.0f);       // y8
    gth[(size_t)b*NTT*GTH + idx] = (_Float16)v;
  }
}

// ---------------- phase A: pure-h2 fp16 cull, 256 thr, 2 cells/thread ----------------
__global__ __launch_bounds__(256) void region_confmask_kernel(
    const float* __restrict__ outp, const _Float16* __restrict__ gth,
    const float* __restrict__ gts_neg, const int* __restrict__ nvalid,
    unsigned int* __restrict__ maskw, double* __restrict__ partials){
  int b = blockIdx.y;
  int tid = threadIdx.x;
  int c0 = blockIdx.x * 256 + tid;          // [0,1792)
  int c1 = c0 + HALFSPLIT;                  // [1792,3584)
  bool ok1 = (c1 < NANCHT);

  // stage fp16 gt table (2400 B) -> LDS
  __shared__ int sgt_i[NTT*GTH/2] __attribute__((aligned(16)));
  const int* gsrc = (const int*)(gth + (size_t)b*NTT*GTH);
  for (int idx = tid; idx < NTT*GTH/2; idx += 256) sgt_i[idx] = gsrc[idx];
  const _Float16* sgt = (const _Float16*)sgt_i;

  // prologue: packed fp16 pred corners for both cells
  h2 Pxp0[4], Pyp0[4], Pt0, Pxp1[4], Pyp1[4], Pt1;
  float cf0, cf1 = 0.0f;
  {
    int a = c0 / NPIX, rem = c0 - a*NPIX;
    int j = rem / NWW, i = rem - j*NWW;
    const float* base = outp + (((size_t)b*NANC + a)*CHC)*NPIX + rem;
    float px8 = 0.0f, py8 = 0.0f;
#pragma unroll
    for (int k = 0; k < KK; ++k){
      float rx = base[(2*k)*NPIX], ry = base[(2*k+1)*NPIX];
      if (k == 0){ rx = sigmoidf_(rx); ry = sigmoidf_(ry); }
      float px = (rx + (float)i)*SXW, py = (ry + (float)j)*SYH;
      if (k < 8){ Pxp0[k>>1][k&1] = (_Float16)px; Pyp0[k>>1][k&1] = (_Float16)py; }
      else { px8 = px; py8 = py; }
    }
    Pt0 = (h2){(_Float16)px8, (_Float16)py8};
    cf0 = sigmoidf_(base[(2*KK)*NPIX]);
  }
  if (ok1){
    int a = c1 / NPIX, rem = c1 - a*NPIX;
    int j = rem / NWW, i = rem - j*NWW;
    const float* base = outp + (((size_t)b*NANC + a)*CHC)*NPIX + rem;
    float px8 = 0.0f, py8 = 0.0f;
#pragma unroll
    for (int k = 0; k < KK; ++k){
      float rx = base[(2*k)*NPIX], ry = base[(2*k+1)*NPIX];
      if (k == 0){ rx = sigmoidf_(rx); ry = sigmoidf_(ry); }
      float px = (rx + (float)i)*SXW, py = (ry + (float)j)*SYH;
      if (k < 8){ Pxp1[k>>1][k&1] = (_Float16)px; Pyp1[k>>1][k&1] = (_Float16)py; }
      else { px8 = px; py8 = py; }
    }
    Pt1 = (h2){(_Float16)px8, (_Float16)py8};
    cf1 = sigmoidf_(base[(2*KK)*NPIX]);
  } else {
#pragma unroll
    for (int p = 0; p < 4; ++p){ Pxp1[p] = (h2){0,0}; Pyp1[p] = (h2){0,0}; }
    Pt1 = (h2){0,0};
  }
  __syncthreads();

  const _Float16 TH16 = (_Float16)CULL_H;
  int nv = nvalid[b];
  unsigned long long q0 = 0ull, q1 = 0ull;
#pragma unroll 2
  for (int t = 0; t < nv; ++t){
    const _Float16* gt = sgt + t*GTH;
    i4 X = *(const i4*)(gt);            // ds_read_b128: x0..x7
    i4 Y = *(const i4*)(gt + 8);        // ds_read_b128: y0..y7
    int T = *(const int*)(gt + 16);     // ds_read_b32 : x8,y8
    h2 gx[4] = {bch2(X.x), bch2(X.y), bch2(X.z), bch2(X.w)};
    h2 gy[4] = {bch2(Y.x), bch2(Y.y), bch2(Y.z), bch2(Y.w)};
    h2 gT = bch2(T);
    unsigned long long bit = 1ull << t;
    // cell 0 — pure h2 dataflow, no shuffles
    {
      h2 dx = Pxp0[0] + gx[0], dy = Pyp0[0] + gy[0];
      h2 m  = __builtin_elementwise_fma(dy, dy, dx*dx);
#pragma unroll
      for (int p = 1; p < 4; ++p){
        dx = Pxp0[p] + gx[p]; dy = Pyp0[p] + gy[p];
        m = __builtin_elementwise_min(m, __builtin_elementwise_fma(dy, dy, dx*dx));
      }
      h2 dt = Pt0 + gT; h2 rt = dt*dt;
      _Float16 mm = hmin(hmin(m[0], m[1]), (_Float16)(rt[0] + rt[1]));
      if (mm < TH16) q0 |= bit;
    }
    // cell 1
    {
      h2 dx = Pxp1[0] + gx[0], dy = Pyp1[0] + gy[0];
      h2 m  = __builtin_elementwise_fma(dy, dy, dx*dx);
#pragma unroll
      for (int p = 1; p < 4; ++p){
        dx = Pxp1[p] + gx[p]; dy = Pyp1[p] + gy[p];
        m = __builtin_elementwise_min(m, __builtin_elementwise_fma(dy, dy, dx*dx));
      }
      h2 dt = Pt1 + gT; h2 rt = dt*dt;
      _Float16 mm = hmin(hmin(m[0], m[1]), (_Float16)(rt[0] + rt[1]));
      if (mm < TH16) q1 |= bit;
    }
  }
  if (!ok1) q1 = 0ull;

  // rare exact path: reload fp32 corners, bit-exact R0 math
  int m0_0 = 1, m0_1 = 1;
  if (__any((q0 | q1) != 0ull)){
    const float* gbase = gts_neg + (size_t)b*NTT*GTS;
    if (q0){
      int a = c0 / NPIX, rem = c0 - a*NPIX;
      int j = rem / NWW, i = rem - j*NWW;
      const float* base = outp + (((size_t)b*NANC + a)*CHC)*NPIX + rem;
      float Pxf[KK], Pyf[KK];
#pragma unroll
      for (int k = 0; k < KK; ++k){
        float rx = base[(2*k)*NPIX], ry = base[(2*k+1)*NPIX];
        if (k == 0){ rx = sigmoidf_(rx); ry = sigmoidf_(ry); }
        Pxf[k] = (rx + (float)i)*SXW; Pyf[k] = (ry + (float)j)*SYH;
      }
      bool exc = false;
      while (q0){
        int t = __ffsll((long long)q0) - 1; q0 &= q0 - 1;
        const float* gg = gbase + t*GTS;
        float s = 0.0f;
#pragma unroll
        for (int k = 0; k < KK; ++k){
          float dx = Pxf[k] + gg[k], dy = Pyf[k] + gg[10+k];
          float d  = fast_sqrt(fmaf(dy, dy, dx*dx));
          float e  = fast_exp2(fmaf(d, -K2C, K1C));
          s += fmaxf(e, 1.0f);
        }
        exc |= (s > THRESH_S);
      }
      if (exc) m0_0 = 0;
    }
    if (q1){
      int a = c1 / NPIX, rem = c1 - a*NPIX;
      int j = rem / NWW, i = rem - j*NWW;
      const float* base = outp + (((size_t)b*NANC + a)*CHC)*NPIX + rem;
      float Pxf[KK], Pyf[KK];
#pragma unroll
      for (int k = 0; k < KK; ++k){
        float rx = base[(2*k)*NPIX], ry = base[(2*k+1)*NPIX];
        if (k == 0){ rx = sigmoidf_(rx); ry = sigmoidf_(ry); }
        Pxf[k] = (rx + (float)i)*SXW; Pyf[k] = (ry + (float)j)*SYH;
      }
      bool exc = false;
      while (q1){
        int t = __ffsll((long long)q1) - 1; q1 &= q1 - 1;
        const float* gg = gbase + t*GTS;
        float s = 0.0f;
#pragma unroll
        for (int k = 0; k < KK; ++k){
          float dx = Pxf[k] + gg[k], dy = Pyf[k] + gg[10+k];
          float d  = fast_sqrt(fmaf(dy, dy, dx*dx));
          float e  = fast_exp2(fmaf(d, -K2C, K1C));
          s += fmaxf(e, 1.0f);
        }
        exc |= (s > THRESH_S);
      }
      if (exc) m0_1 = 0;
    }
  }

  float contrib = (m0_0 ? 0.5f*cf0*cf0 : 0.0f) + ((ok1 && m0_1) ? 0.5f*cf1*cf1 : 0.0f);

  // bit-packed mask writes
  int lane = tid & 63;
  int wavebase0 = blockIdx.x * 256 + (tid & ~63);
  unsigned long long mb0 = __ballot(m0_0 != 0);
  if ((lane & 31) == 0){
    unsigned int w = (lane == 0) ? (unsigned int)mb0 : (unsigned int)(mb0 >> 32);
    maskw[(size_t)b*MWPB + (wavebase0 >> 5) + (lane >> 5)] = w;
  }
  unsigned long long mb1 = __ballot(m0_1 != 0);
  int wavebase1 = wavebase0 + HALFSPLIT;
  if ((lane & 31) == 0 && wavebase1 < NANCHT){
    unsigned int w = (lane == 0) ? (unsigned int)mb1 : (unsigned int)(mb1 >> 32);
    maskw[(size_t)b*MWPB + (wavebase1 >> 5) + (lane >> 5)] = w;
  }

  // block reduce -> one double partial per block
#pragma unroll
  for (int o = 32; o > 0; o >>= 1) contrib += __shfl_xor(contrib, o, 64);
  __shared__ float wsum[4];
  int wid = tid >> 6;
  if (lane == 0) wsum[wid] = contrib;
  __syncthreads();
  if (tid == 0){
    double tot = (double)wsum[0] + (double)wsum[1] + (double)wsum[2] + (double)wsum[3];
    partials[b*NBLK + blockIdx.x] = tot;
  }
}

// ---------------- phase B+C: scatter winners + small losses ----------------
__global__ __launch_bounds__(64) void scatter_loss_kernel(
    const float* __restrict__ outp, const float* __restrict__ tgt,
    const int* __restrict__ nvalid, const unsigned int* __restrict__ maskw,
    double* __restrict__ bc_part){
  int b = blockIdx.x;
  int t = threadIdx.x;
  __shared__ int keys[NTT];
  int nv = nvalid[b];
  bool valid = (t < nv);

  int key = -1, gi0 = 0, gj0 = 0, bn = 0;
  float txv[KK], tyv[KK];
  float conf_t = 0.0f, tcls = 0.0f;

  if (t < NTT){
    const float* trow = tgt + ((size_t)b*NTT + t)*LL;
    tcls = trow[0];
    float gx0 = trow[1]*(float)NWW;
    float gy0 = trow[2]*(float)NHH;
    gi0 = min(max((int)floorf(gx0), 0), NWW-1);
    gj0 = min(max((int)floorf(gy0), 0), NHH-1);
#pragma unroll
    for (int k = 0; k < KK; ++k){
      txv[k] = trow[1+2*k]*(float)NWW - (float)gi0;
      tyv[k] = trow[2+2*k]*(float)NHH - (float)gj0;
    }
    float gw = trow[LL-2]*(float)NWW, gh = trow[LL-1]*(float)NHH;
    float best = -1.0f;
    for (int a = 0; a < NANC; ++a){
      float aw = c_anch[2*a], ah = c_anch[2*a+1];
      float inter = fminf(aw, gw) * fminf(ah, gh);
      float iou = inter / (aw*ah + gw*gh - inter);
      if (iou > best){ best = iou; bn = a; }
    }
    key = bn*NPIX + gj0*NWW + gi0;
    keys[t] = key;

    long f = (long)b*NANCHT - NPIX + gj0*NWW + gi0;
    if (f < 0) f += NCELLT;
    int bb  = (int)(f / NANCHT);
    int rr  = (int)(f - (long)bb*NANCHT);
    int aa  = rr / NPIX;
    int rr2 = rr - aa*NPIX;
    int jj  = rr2 / NWW;
    int ii  = rr2 - jj*NWW;
    const float* pbase = outp + (((size_t)bb*NANC + aa)*CHC)*NPIX + rr2;
    float s = 0.0f;
#pragma unroll
    for (int k = 0; k < KK; ++k){
      float rx = pbase[(2*k)*NPIX], ry = pbase[(2*k+1)*NPIX];
      if (k == 0){ rx = sigmoidf_(rx); ry = sigmoidf_(ry); }
      float Pxx = (rx + (float)ii)*SXW, Pyy = (ry + (float)jj)*SYH;
      float dx = Pxx - trow[1+2*k]*640.0f;
      float dy = Pyy - trow[2+2*k]*480.0f;
      float d  = fast_sqrt(fmaf(dy, dy, dx*dx));
      float e  = fast_exp2(fmaf(d, -K2C, K1C));
      s += fmaxf(e, 1.0f);
    }
    conf_t = (s - 9.0f) * CONF_T_SCALE;
  }
  __syncthreads();

  bool winner = valid;
  if (valid){
    for (int u = t+1; u < nv; ++u) if (keys[u] == key){ winner = false; break; }
  }

  double lx = 0.0, ly = 0.0, lcls = 0.0, lcf = 0.0;
  if (winner){
    const float* cbase = outp + (((size_t)b*NANC + bn)*CHC)*NPIX + gj0*NWW + gi0;
    float sx = 0.0f, sy = 0.0f;
#pragma unroll
    for (int k = 0; k < KK; ++k){
      float rx = cbase[(2*k)*NPIX], ry = cbase[(2*k+1)*NPIX];
      if (k == 0){ rx = sigmoidf_(rx); ry = sigmoidf_(ry); }
      float dx = rx - txv[k], dy = ry - tyv[k];
      sx = fmaf(dx, dx, sx); sy = fmaf(dy, dy, sy);
    }
    lx = 0.5*(double)sx; ly = 0.5*(double)sy;

    float lg[NCLS], mx = -1e30f;
#pragma unroll
    for (int c = 0; c < NCLS; ++c){ lg[c] = cbase[(2*KK+1+c)*NPIX]; mx = fmaxf(mx, lg[c]); }
    float se = 0.0f;
#pragma unroll
    for (int c = 0; c < NCLS; ++c) se += fast_exp2((lg[c]-mx)*LOG2E_F);
    int label = min(max((int)tcls, 0), NCLS-1);
    lcls = (double)(mx + logf(se) - lg[label]);

    float cf = sigmoidf_(cbase[(2*KK)*NPIX]);
    int idx = bn*NPIX + gj0*NWW + gi0;
    int m0 = (maskw[(size_t)b*MWPB + (idx >> 5)] >> (idx & 31)) & 1;
    float dcf = cf - conf_t;
    lcf = 0.5*OBJ_W*(double)(dcf*dcf) - (m0 ? 0.5*(double)(cf*cf) : 0.0);
  }

#pragma unroll
  for (int o = 32; o > 0; o >>= 1){
    lx  += __shfl_xor(lx,  o, 64);
    ly  += __shfl_xor(ly,  o, 64);
    lcls+= __shfl_xor(lcls,o, 64);
    lcf += __shfl_xor(lcf, o, 64);
  }
  if (threadIdx.x == 0){
    double* bp = bc_part + (size_t)b*4;
    bp[0] = lx; bp[1] = ly; bp[2] = lcls; bp[3] = lcf;
  }
}

// ---------------- finalize ----------------
__global__ __launch_bounds__(256) void finalize_kernel(
    const double* __restrict__ bc_part, const double* __restrict__ partials,
    const int* __restrict__ epoch_p, float* __restrict__ outv){
  int tid = threadIdx.x;
  double vx=0, vy=0, vc=0, vf=0, vb=0;
  for (int i = tid; i < NBB; i += 256){
    vx += bc_part[4*i]; vy += bc_part[4*i+1];
    vc += bc_part[4*i+2]; vf += bc_part[4*i+3];
  }
  for (int i = tid; i < NBLK*NBB; i += 256) vb += partials[i];
#pragma unroll
  for (int o = 32; o > 0; o >>= 1){
    vx += __shfl_xor(vx, o, 64); vy += __shfl_xor(vy, o, 64);
    vc += __shfl_xor(vc, o, 64); vf += __shfl_xor(vf, o, 64);
    vb += __shfl_xor(vb, o, 64);
  }
  __shared__ double sm[5][4];
  int wid = tid >> 6, lane = tid & 63;
  if (lane == 0){ sm[0][wid]=vx; sm[1][wid]=vy; sm[2][wid]=vc; sm[3][wid]=vf; sm[4][wid]=vb; }
  __syncthreads();
  if (tid == 0){
    double fx=0, fy=0, fc=0, ff=0, fb=0;
    for (int w = 0; w < 4; ++w){ fx+=sm[0][w]; fy+=sm[1][w]; fc+=sm[2][w]; ff+=sm[3][w]; fb+=sm[4][w]; }
    double loss = fx + fy + fc;
    if (*epoch_p > EPOCH_PRETRAIN) loss += ff + fb;
    outv[0] = (float)loss;
  }
}

extern "C" void kernel_launch(void* const* d_in, const int* in_sizes, int n_in,
                              void* d_out, int out_size, void* d_ws, size_t ws_size,
                              hipStream_t stream){
  (void)in_sizes; (void)n_in; (void)out_size; (void)ws_size;
  const float* outp = (const float*)d_in[0];
  const float* tgt  = (const float*)d_in[1];
  const int*   ep   = (const int*)d_in[2];
  float* outv = (float*)d_out;
  char* ws = (char*)d_ws;

  double* bc_part   = (double*)(ws);                    // 4096 B
  double* partials  = (double*)(ws + 4096);             // 7168 B
  float*  gts_neg   = (float*) (ws + 11264);            // 512000 B
  int*    nvalid    = (int*)   (ws + 523264);           // 512 B
  unsigned int* maskw = (unsigned int*)(ws + 523776);   // 54272 B
  _Float16* gth     = (_Float16*)(ws + 578048);         // 307200 B

  prep_kernel<<<dim3(NBB), dim3(64), 0, stream>>>(tgt, gts_neg, gth, nvalid);
  region_confmask_kernel<<<dim3(NBLK, NBB), dim3(256), 0, stream>>>(outp, gth, gts_neg, nvalid, maskw, partials);
  scatter_loss_kernel<<<dim3(NBB), dim3(64), 0, stream>>>(outp, tgt, nvalid, maskw, bc_part);
  finalize_kernel<<<dim3(1), dim3(256), 0, stream>>>(bc_part, partials, ep, outv);
}

// Round 6
// 142.657 us; speedup vs baseline: 1.0508x; 1.0508x over previous
//
#include <hip/hip_runtime.h>
#include <math.h>

// ---------------- problem constants ----------------
#define KK     9
#define NCLS   13
#define NANC   5
#define NBB    128
#define NHH    26
#define NWW    26
#define NTT    50
#define LL     21
#define CHC    32
#define NPIX   676
#define NANCHT 3380
#define NCELLT 432640
#define GTS    20     // floats per target, fp32 exact-path table [x0..x8,BIG,y0..y8,BIG]
#define TROWS  52     // fp16 table rows (50 + inf padding -> branchless 13x4 chunks)
#define GTW    10     // u32 words per fp16 row: x01,x23,x45,x67,x8+inf | y01,...,y8+inf
#define MWPB   106    // mask words per batch
#define HALFSPLIT 1792
#define NBLK   14     // confmask grid.x (14*128 = 1792 threads, 2 cells each)

// derived float constants
#define LOG2E_F   1.4426950408889634f
#define K1C       2.8853900817779268f   // SHARP*log2e
#define K2C       0.036067376022224085f // K1C/TH
#define SXW       24.615384615384617f   // 640/26
#define SYH       18.461538461538463f   // 480/26
#define THRESH_S  43.500902934225507f   // 9 + SIL*9*(e^2-1)
#define CULL_H    400.0f                // conservative fp16 cull (true cut 288.25 + fp16 abs err)
#define CONF_T_SCALE 0.017390849194407297f
#define OBJ_W     5.0f
#define EPOCH_PRETRAIN 15
#define BIGV      6.0e18f
#define INFH      0x7C00u               // fp16 +inf
#define INFH2     0x7C007C00u

typedef _Float16 h2 __attribute__((ext_vector_type(2)));

static __device__ __forceinline__ float fast_exp2(float x){ return __builtin_amdgcn_exp2f(x); }
static __device__ __forceinline__ float fast_sqrt(float x){ return __builtin_amdgcn_sqrtf(x); }
static __device__ __forceinline__ float sigmoidf_(float x){
  return 1.0f/(1.0f + fast_exp2(-LOG2E_F*x));
}
// forced packed-fp16 ops (compiler scalarizes vector types; asm guarantees v_pk_*)
static __device__ __forceinline__ int pk_add_sv(int s, int v){
  int d; asm("v_pk_add_f16 %0, %1, %2" : "=v"(d) : "s"(s), "v"(v)); return d;
}
static __device__ __forceinline__ int pk_mul_vv(int a, int b){
  int d; asm("v_pk_mul_f16 %0, %1, %2" : "=v"(d) : "v"(a), "v"(b)); return d;
}
static __device__ __forceinline__ int pk_fma_vvv(int a, int b, int c){
  int d; asm("v_pk_fma_f16 %0, %1, %2, %3" : "=v"(d) : "v"(a), "v"(b), "v"(c)); return d;
}
static __device__ __forceinline__ int pk_min_vv(int a, int b){
  int d; asm("v_pk_min_f16 %0, %1, %2" : "=v"(d) : "v"(a), "v"(b)); return d;
}
static __device__ __forceinline__ unsigned short f2h_bits(float v){
  return __builtin_bit_cast(unsigned short, (_Float16)v);
}

__constant__ float c_anch[10] = {1.482f,2.2412f,2.0501f,3.1265f,2.3946f,4.6891f,
                                 3.1018f,3.991f,3.4879f,5.8851f};

// ws layout (bytes):
//   [0,4096)         : bc_part  double[NBB][4]
//   [4096,18432)     : partials double[NBLK*NBB]
//   [18432,530432)   : gts_neg  float[NBB*NTT*GTS]  fp32 NEGATED px corners
//   [530432,530944)  : nvalid   int[NBB]
//   [530944,585216)  : maskw    u32[NBB*MWPB]
//   [585216,851456)  : gthw     u32[NBB*TROWS*GTW]  packed fp16 NEGATED px corners (inf-padded)

// ---------------- phase 0: prep ----------------
__global__ __launch_bounds__(64) void prep_kernel(const float* __restrict__ tgt,
                                                  float* __restrict__ gts_neg,
                                                  unsigned* __restrict__ gthw,
                                                  int* __restrict__ nvalid){
  int b = blockIdx.x;
  int t = threadIdx.x;
  const float* trow = tgt + (size_t)b*NTT*LL;
  float v1 = (t < NTT) ? trow[t*LL + 1] : 0.0f;
  unsigned long long mk = __ballot(t < NTT && v1 != 0.0f);
  int nv = __ffsll(~mk) - 1;                 // cumprod-valid prefix length
  if (t == 0) nvalid[b] = nv;
  // fp32 exact table (50 rows)
  for (int idx = t; idx < NTT*GTS; idx += 64){
    int tt = idx / GTS;
    int c  = idx - tt*GTS;
    float v;
    if (c == 9 || c == 19)      v = BIGV;
    else if (c < 9)             v = -(trow[tt*LL + 1 + 2*c] * 640.0f);
    else                        v = -(trow[tt*LL + 2 + 2*(c-10)] * 480.0f);
    gts_neg[(size_t)b*NTT*GTS + idx] = v;
  }
  // packed fp16 table (52 rows, rows >= nv are all +inf)
  if (t < TROWS){
    unsigned w[GTW];
    if (t < nv){
      const float* tr = trow + t*LL;
      float xs[KK], ys[KK];
#pragma unroll
      for (int k = 0; k < KK; ++k){
        xs[k] = -(tr[1+2*k] * 640.0f);
        ys[k] = -(tr[2+2*k] * 480.0f);
      }
#pragma unroll
      for (int p = 0; p < 4; ++p){
        w[p]   = (unsigned)f2h_bits(xs[2*p]) | ((unsigned)f2h_bits(xs[2*p+1]) << 16);
        w[5+p] = (unsigned)f2h_bits(ys[2*p]) | ((unsigned)f2h_bits(ys[2*p+1]) << 16);
      }
      w[4] = (unsigned)f2h_bits(xs[8]) | (INFH << 16);
      w[9] = (unsigned)f2h_bits(ys[8]) | (INFH << 16);
    } else {
#pragma unroll
      for (int p = 0; p < GTW; ++p) w[p] = INFH2;
    }
    unsigned* dst = gthw + ((size_t)b*TROWS + t)*GTW;
#pragma unroll
    for (int p = 0; p < GTW; ++p) dst[p] = w[p];
  }
}

// ---------------- phase A: asm-pk fp16 cull (SGPR gt), LDS fp32 exact path ----------------
__global__ __launch_bounds__(128) void region_confmask_kernel(
    const float* __restrict__ outp, const unsigned* __restrict__ gthw,
    const float* __restrict__ gts_neg, unsigned int* __restrict__ maskw,
    double* __restrict__ partials){
  int b = blockIdx.y;
  int tid = threadIdx.x;
  int c0 = blockIdx.x * 128 + tid;          // [0,1792)
  int c1 = c0 + HALFSPLIT;                  // [1792,3584)
  bool ok1 = (c1 < NANCHT);

  // stage fp32 exact table -> LDS (4000 B)
  __shared__ float sgt[NTT*GTS] __attribute__((aligned(16)));
  {
    const float* g32 = gts_neg + (size_t)b*NTT*GTS;
    for (int idx = tid; idx < NTT*GTS; idx += 128) sgt[idx] = g32[idx];
  }

  // prologue: fp32 pred corners (kept for exact path) + packed fp16 words
  float Pxf0[KK], Pyf0[KK], Pxf1[KK], Pyf1[KK];
  int Pxw0[5], Pyw0[5], Pxw1[5], Pyw1[5];
  float cf0, cf1 = 0.0f;
  {
    int a = c0 / NPIX, rem = c0 - a*NPIX;
    int j = rem / NWW, i = rem - j*NWW;
    const float* base = outp + (((size_t)b*NANC + a)*CHC)*NPIX + rem;
#pragma unroll
    for (int k = 0; k < KK; ++k){
      float rx = base[(2*k)*NPIX], ry = base[(2*k+1)*NPIX];
      if (k == 0){ rx = sigmoidf_(rx); ry = sigmoidf_(ry); }
      Pxf0[k] = (rx + (float)i)*SXW; Pyf0[k] = (ry + (float)j)*SYH;
    }
    cf0 = sigmoidf_(base[(2*KK)*NPIX]);
  }
  if (ok1){
    int a = c1 / NPIX, rem = c1 - a*NPIX;
    int j = rem / NWW, i = rem - j*NWW;
    const float* base = outp + (((size_t)b*NANC + a)*CHC)*NPIX + rem;
#pragma unroll
    for (int k = 0; k < KK; ++k){
      float rx = base[(2*k)*NPIX], ry = base[(2*k+1)*NPIX];
      if (k == 0){ rx = sigmoidf_(rx); ry = sigmoidf_(ry); }
      Pxf1[k] = (rx + (float)i)*SXW; Pyf1[k] = (ry + (float)j)*SYH;
    }
    cf1 = sigmoidf_(base[(2*KK)*NPIX]);
  } else {
#pragma unroll
    for (int k = 0; k < KK; ++k){ Pxf1[k] = 0.0f; Pyf1[k] = 0.0f; }
  }
#pragma unroll
  for (int p = 0; p < 4; ++p){
    Pxw0[p] = (unsigned)f2h_bits(Pxf0[2*p]) | ((unsigned)f2h_bits(Pxf0[2*p+1]) << 16);
    Pyw0[p] = (unsigned)f2h_bits(Pyf0[2*p]) | ((unsigned)f2h_bits(Pyf0[2*p+1]) << 16);
    Pxw1[p] = (unsigned)f2h_bits(Pxf1[2*p]) | ((unsigned)f2h_bits(Pxf1[2*p+1]) << 16);
    Pyw1[p] = (unsigned)f2h_bits(Pyf1[2*p]) | ((unsigned)f2h_bits(Pyf1[2*p+1]) << 16);
  }
  Pxw0[4] = (unsigned)f2h_bits(Pxf0[8]); Pyw0[4] = (unsigned)f2h_bits(Pyf0[8]); // hi=0 vs inf pad
  Pxw1[4] = (unsigned)f2h_bits(Pxf1[8]); Pyw1[4] = (unsigned)f2h_bits(Pyf1[8]);
  __syncthreads();

  // cull loop: 13 chunks x 4 targets, gt words via uniform s_load, forced v_pk_* math
  const _Float16 TH16 = (_Float16)CULL_H;
  const unsigned* gsrc = gthw + (size_t)b*TROWS*GTW;
  unsigned long long q0 = 0ull, q1 = 0ull;
#pragma unroll 1
  for (int c = 0; c < 13; ++c){
    int G[40];
#pragma unroll
    for (int w = 0; w < 40; ++w) G[w] = (int)gsrc[c*40 + w];   // uniform -> s_load
#pragma unroll
    for (int u = 0; u < 4; ++u){
      int t = c*4 + u;
      unsigned long long bit = 1ull << t;
      // cell 0
      {
        int dx = pk_add_sv(G[u*10+0], Pxw0[0]); int r = pk_mul_vv(dx,dx);
        int dy = pk_add_sv(G[u*10+5], Pyw0[0]); r = pk_fma_vvv(dy,dy,r);
        int m = r;
#pragma unroll
        for (int p = 1; p < 5; ++p){
          dx = pk_add_sv(G[u*10+p],   Pxw0[p]); r = pk_mul_vv(dx,dx);
          dy = pk_add_sv(G[u*10+5+p], Pyw0[p]); r = pk_fma_vvv(dy,dy,r);
          m = pk_min_vv(m, r);
        }
        h2 mh = __builtin_bit_cast(h2, m);
        if ((mh[0] < TH16) | (mh[1] < TH16)) q0 |= bit;
      }
      // cell 1
      {
        int dx = pk_add_sv(G[u*10+0], Pxw1[0]); int r = pk_mul_vv(dx,dx);
        int dy = pk_add_sv(G[u*10+5], Pyw1[0]); r = pk_fma_vvv(dy,dy,r);
        int m = r;
#pragma unroll
        for (int p = 1; p < 5; ++p){
          dx = pk_add_sv(G[u*10+p],   Pxw1[p]); r = pk_mul_vv(dx,dx);
          dy = pk_add_sv(G[u*10+5+p], Pyw1[p]); r = pk_fma_vvv(dy,dy,r);
          m = pk_min_vv(m, r);
        }
        h2 mh = __builtin_bit_cast(h2, m);
        if ((mh[0] < TH16) | (mh[1] < TH16)) q1 |= bit;
      }
    }
  }
  if (!ok1) q1 = 0ull;

  // exact path (bit-exact R0 math), gt from LDS
  int m0_0 = 1, m0_1 = 1;
  {
    bool e0 = false, e1 = false;
    while (q0){
      int t = __ffsll((long long)q0) - 1; q0 &= q0 - 1;
      const float* gg = sgt + t*GTS;
      float s = 0.0f;
#pragma unroll
      for (int k = 0; k < KK; ++k){
        float dx = Pxf0[k] + gg[k], dy = Pyf0[k] + gg[10+k];
        float d  = fast_sqrt(fmaf(dy, dy, dx*dx));
        float e  = fast_exp2(fmaf(d, -K2C, K1C));
        s += fmaxf(e, 1.0f);
      }
      e0 |= (s > THRESH_S);
    }
    while (q1){
      int t = __ffsll((long long)q1) - 1; q1 &= q1 - 1;
      const float* gg = sgt + t*GTS;
      float s = 0.0f;
#pragma unroll
      for (int k = 0; k < KK; ++k){
        float dx = Pxf1[k] + gg[k], dy = Pyf1[k] + gg[10+k];
        float d  = fast_sqrt(fmaf(dy, dy, dx*dx));
        float e  = fast_exp2(fmaf(d, -K2C, K1C));
        s += fmaxf(e, 1.0f);
      }
      e1 |= (s > THRESH_S);
    }
    if (e0) m0_0 = 0;
    if (e1) m0_1 = 0;
  }

  float contrib = (m0_0 ? 0.5f*cf0*cf0 : 0.0f) + ((ok1 && m0_1) ? 0.5f*cf1*cf1 : 0.0f);

  // bit-packed mask writes
  int lane = tid & 63;
  int wavebase0 = blockIdx.x * 128 + (tid & ~63);
  unsigned long long mb0 = __ballot(m0_0 != 0);
  if ((lane & 31) == 0){
    unsigned int w = (lane == 0) ? (unsigned int)mb0 : (unsigned int)(mb0 >> 32);
    maskw[(size_t)b*MWPB + (wavebase0 >> 5) + (lane >> 5)] = w;
  }
  unsigned long long mb1 = __ballot(m0_1 != 0);
  int wavebase1 = wavebase0 + HALFSPLIT;
  if ((lane & 31) == 0 && wavebase1 < NANCHT){
    unsigned int w = (lane == 0) ? (unsigned int)mb1 : (unsigned int)(mb1 >> 32);
    maskw[(size_t)b*MWPB + (wavebase1 >> 5) + (lane >> 5)] = w;
  }

  // block reduce -> one double partial per block
#pragma unroll
  for (int o = 32; o > 0; o >>= 1) contrib += __shfl_xor(contrib, o, 64);
  __shared__ float wsum[2];
  int wid = tid >> 6;
  if (lane == 0) wsum[wid] = contrib;
  __syncthreads();
  if (tid == 0)
    partials[b*NBLK + blockIdx.x] = (double)wsum[0] + (double)wsum[1];
}

// ---------------- phase B+C: scatter winners + small losses ----------------
__global__ __launch_bounds__(64) void scatter_loss_kernel(
    const float* __restrict__ outp, const float* __restrict__ tgt,
    const int* __restrict__ nvalid, const unsigned int* __restrict__ maskw,
    double* __restrict__ bc_part){
  int b = blockIdx.x;
  int t = threadIdx.x;
  __shared__ int keys[NTT];
  int nv = nvalid[b];
  bool valid = (t < nv);

  int key = -1, gi0 = 0, gj0 = 0, bn = 0;
  float txv[KK], tyv[KK];
  float conf_t = 0.0f, tcls = 0.0f;

  if (t < NTT){
    const float* trow = tgt + ((size_t)b*NTT + t)*LL;
    tcls = trow[0];
    float gx0 = trow[1]*(float)NWW;
    float gy0 = trow[2]*(float)NHH;
    gi0 = min(max((int)floorf(gx0), 0), NWW-1);
    gj0 = min(max((int)floorf(gy0), 0), NHH-1);
#pragma unroll
    for (int k = 0; k < KK; ++k){
      txv[k] = trow[1+2*k]*(float)NWW - (float)gi0;
      tyv[k] = trow[2+2*k]*(float)NHH - (float)gj0;
    }
    float gw = trow[LL-2]*(float)NWW, gh = trow[LL-1]*(float)NHH;
    float best = -1.0f;
    for (int a = 0; a < NANC; ++a){
      float aw = c_anch[2*a], ah = c_anch[2*a+1];
      float inter = fminf(aw, gw) * fminf(ah, gh);
      float iou = inter / (aw*ah + gw*gh - inter);
      if (iou > best){ best = iou; bn = a; }
    }
    key = bn*NPIX + gj0*NWW + gi0;
    keys[t] = key;

    long f = (long)b*NANCHT - NPIX + gj0*NWW + gi0;
    if (f < 0) f += NCELLT;
    int bb  = (int)(f / NANCHT);
    int rr  = (int)(f - (long)bb*NANCHT);
    int aa  = rr / NPIX;
    int rr2 = rr - aa*NPIX;
    int jj  = rr2 / NWW;
    int ii  = rr2 - jj*NWW;
    const float* pbase = outp + (((size_t)bb*NANC + aa)*CHC)*NPIX + rr2;
    float s = 0.0f;
#pragma unroll
    for (int k = 0; k < KK; ++k){
      float rx = pbase[(2*k)*NPIX], ry = pbase[(2*k+1)*NPIX];
      if (k == 0){ rx = sigmoidf_(rx); ry = sigmoidf_(ry); }
      float Pxx = (rx + (float)ii)*SXW, Pyy = (ry + (float)jj)*SYH;
      float dx = Pxx - trow[1+2*k]*640.0f;
      float dy = Pyy - trow[2+2*k]*480.0f;
      float d  = fast_sqrt(fmaf(dy, dy, dx*dx));
      float e  = fast_exp2(fmaf(d, -K2C, K1C));
      s += fmaxf(e, 1.0f);
    }
    conf_t = (s - 9.0f) * CONF_T_SCALE;
  }
  __syncthreads();

  bool winner = valid;
  if (valid){
    for (int u = t+1; u < nv; ++u) if (keys[u] == key){ winner = false; break; }
  }

  double lx = 0.0, ly = 0.0, lcls = 0.0, lcf = 0.0;
  if (winner){
    const float* cbase = outp + (((size_t)b*NANC + bn)*CHC)*NPIX + gj0*NWW + gi0;
    float sx = 0.0f, sy = 0.0f;
#pragma unroll
    for (int k = 0; k < KK; ++k){
      float rx = cbase[(2*k)*NPIX], ry = cbase[(2*k+1)*NPIX];
      if (k == 0){ rx = sigmoidf_(rx); ry = sigmoidf_(ry); }
      float dx = rx - txv[k], dy = ry - tyv[k];
      sx = fmaf(dx, dx, sx); sy = fmaf(dy, dy, sy);
    }
    lx = 0.5*(double)sx; ly = 0.5*(double)sy;

    float lg[NCLS], mx = -1e30f;
#pragma unroll
    for (int c = 0; c < NCLS; ++c){ lg[c] = cbase[(2*KK+1+c)*NPIX]; mx = fmaxf(mx, lg[c]); }
    float se = 0.0f;
#pragma unroll
    for (int c = 0; c < NCLS; ++c) se += fast_exp2((lg[c]-mx)*LOG2E_F);
    int label = min(max((int)tcls, 0), NCLS-1);
    lcls = (double)(mx + logf(se) - lg[label]);

    float cf = sigmoidf_(cbase[(2*KK)*NPIX]);
    int idx = bn*NPIX + gj0*NWW + gi0;
    int m0 = (maskw[(size_t)b*MWPB + (idx >> 5)] >> (idx & 31)) & 1;
    float dcf = cf - conf_t;
    lcf = 0.5*OBJ_W*(double)(dcf*dcf) - (m0 ? 0.5*(double)(cf*cf) : 0.0);
  }

#pragma unroll
  for (int o = 32; o > 0; o >>= 1){
    lx  += __shfl_xor(lx,  o, 64);
    ly  += __shfl_xor(ly,  o, 64);
    lcls+= __shfl_xor(lcls,o, 64);
    lcf += __shfl_xor(lcf, o, 64);
  }
  if (threadIdx.x == 0){
    double* bp = bc_part + (size_t)b*4;
    bp[0] = lx; bp[1] = ly; bp[2] = lcls; bp[3] = lcf;
  }
}

// ---------------- finalize ----------------
__global__ __launch_bounds__(256) void finalize_kernel(
    const double* __restrict__ bc_part, const double* __restrict__ partials,
    const int* __restrict__ epoch_p, float* __restrict__ outv){
  int tid = threadIdx.x;
  double vx=0, vy=0, vc=0, vf=0, vb=0;
  for (int i = tid; i < NBB; i += 256){
    vx += bc_part[4*i]; vy += bc_part[4*i+1];
    vc += bc_part[4*i+2]; vf += bc_part[4*i+3];
  }
  for (int i = tid; i < NBLK*NBB; i += 256) vb += partials[i];
#pragma unroll
  for (int o = 32; o > 0; o >>= 1){
    vx += __shfl_xor(vx, o, 64); vy += __shfl_xor(vy, o, 64);
    vc += __shfl_xor(vc, o, 64); vf += __shfl_xor(vf, o, 64);
    vb += __shfl_xor(vb, o, 64);
  }
  __shared__ double sm[5][4];
  int wid = tid >> 6, lane = tid & 63;
  if (lane == 0){ sm[0][wid]=vx; sm[1][wid]=vy; sm[2][wid]=vc; sm[3][wid]=vf; sm[4][wid]=vb; }
  __syncthreads();
  if (tid == 0){
    double fx=0, fy=0, fc=0, ff=0, fb=0;
    for (int w = 0; w < 4; ++w){ fx+=sm[0][w]; fy+=sm[1][w]; fc+=sm[2][w]; ff+=sm[3][w]; fb+=sm[4][w]; }
    double loss = fx + fy + fc;
    if (*epoch_p > EPOCH_PRETRAIN) loss += ff + fb;
    outv[0] = (float)loss;
  }
}

extern "C" void kernel_launch(void* const* d_in, const int* in_sizes, int n_in,
                              void* d_out, int out_size, void* d_ws, size_t ws_size,
                              hipStream_t stream){
  (void)in_sizes; (void)n_in; (void)out_size; (void)ws_size;
  const float* outp = (const float*)d_in[0];
  const float* tgt  = (const float*)d_in[1];
  const int*   ep   = (const int*)d_in[2];
  float* outv = (float*)d_out;
  char* ws = (char*)d_ws;

  double* bc_part   = (double*)(ws);                    // 4096 B
  double* partials  = (double*)(ws + 4096);             // 14336 B
  float*  gts_neg   = (float*) (ws + 18432);            // 512000 B
  int*    nvalid    = (int*)   (ws + 530432);           // 512 B
  unsigned int* maskw = (unsigned int*)(ws + 530944);   // 54272 B
  unsigned* gthw    = (unsigned*)(ws + 585216);         // 266240 B

  prep_kernel<<<dim3(NBB), dim3(64), 0, stream>>>(tgt, gts_neg, gthw, nvalid);
  region_confmask_kernel<<<dim3(NBLK, NBB), dim3(128), 0, stream>>>(outp, gthw, gts_neg, maskw, partials);
  scatter_loss_kernel<<<dim3(NBB), dim3(64), 0, stream>>>(outp, tgt, nvalid, maskw, bc_part);
  finalize_kernel<<<dim3(1), dim3(256), 0, stream>>>(bc_part, partials, ep, outv);
}

// Round 7
// 140.291 us; speedup vs baseline: 1.0685x; 1.0169x over previous
//
#include <hip/hip_runtime.h>
#include <math.h>

// ---------------- problem constants ----------------
#define KK     9
#define NCLS   13
#define NANC   5
#define NBB    128
#define NHH    26
#define NWW    26
#define NTT    50
#define LL     21
#define CHC    32
#define NPIX   676
#define NANCHT 3380
#define NCELLT 432640
#define GTS    20     // floats per target, fp32 exact-path table [x0..x8,BIG,y0..y8,BIG]
#define TROWS  52     // fp16 table rows (50 + inf padding -> branchless 13x4 chunks)
#define GTW    10     // u32 words per fp16 row: x01,x23,x45,x67,x8|inf, y01..y67, y8|inf
#define MWPB   106    // mask words per batch
#define HALFSPLIT 1792
#define NBLK   14     // confmask grid.x (14*128 = 1792 threads, 2 cells each)

// derived float constants
#define LOG2E_F   1.4426950408889634f
#define K1C       2.8853900817779268f   // SHARP*log2e
#define K2C       0.036067376022224085f // K1C/TH
#define SXW       24.615384615384617f   // 640/26
#define SYH       18.461538461538463f   // 480/26
#define THRESH_S  43.500902934225507f   // 9 + SIL*9*(e^2-1)
#define CONF_T_SCALE 0.017390849194407297f
#define OBJ_W     5.0f
#define EPOCH_PRETRAIN 15
#define BIGV      6.0e18f
#define INFH      0x7C00u               // fp16 +inf
#define INFH2     0x7C007C00u
#define NEG6400W  0xEE40EE40            // packed fp16 {-6400,-6400}
// chord-bound cull: fire exact path iff sum_k max(6400 - r2_k, 0) > 31000
// (true cut 34560 = 5.4*6400; 3560 margin covers worst-case fp16 error ~3100)
#define CULL_FIRE_NEG  -31000.0f

typedef _Float16 h2 __attribute__((ext_vector_type(2)));

static __device__ __forceinline__ float fast_exp2(float x){ return __builtin_amdgcn_exp2f(x); }
static __device__ __forceinline__ float fast_sqrt(float x){ return __builtin_amdgcn_sqrtf(x); }
static __device__ __forceinline__ float sigmoidf_(float x){
  return 1.0f/(1.0f + fast_exp2(-LOG2E_F*x));
}
// forced packed-fp16 ops (compiler scalarizes vector types; asm guarantees v_pk_*)
static __device__ __forceinline__ int pk_add_sv(int s, int v){
  int d; asm("v_pk_add_f16 %0, %1, %2" : "=v"(d) : "s"(s), "v"(v)); return d;
}
static __device__ __forceinline__ int pk_add_vv(int a, int b){
  int d; asm("v_pk_add_f16 %0, %1, %2" : "=v"(d) : "v"(a), "v"(b)); return d;
}
static __device__ __forceinline__ int pk_mul_vv(int a, int b){
  int d; asm("v_pk_mul_f16 %0, %1, %2" : "=v"(d) : "v"(a), "v"(b)); return d;
}
static __device__ __forceinline__ int pk_fma_vvv(int a, int b, int c){
  int d; asm("v_pk_fma_f16 %0, %1, %2, %3" : "=v"(d) : "v"(a), "v"(b), "v"(c)); return d;
}
static __device__ __forceinline__ int pk_min_vv(int a, int b){
  int d; asm("v_pk_min_f16 %0, %1, %2" : "=v"(d) : "v"(a), "v"(b)); return d;
}
static __device__ __forceinline__ unsigned short f2h_bits(float v){
  return __builtin_bit_cast(unsigned short, (_Float16)v);
}

__constant__ float c_anch[10] = {1.482f,2.2412f,2.0501f,3.1265f,2.3946f,4.6891f,
                                 3.1018f,3.991f,3.4879f,5.8851f};

// ws layout (bytes):
//   [0,4096)         : bc_part  double[NBB][4]
//   [4096,18432)     : partials double[NBLK*NBB]
//   [18432,530432)   : gts_neg  float[NBB*NTT*GTS]  fp32 NEGATED px corners
//   [530432,530944)  : nvalid   int[NBB]
//   [530944,585216)  : maskw    u32[NBB*MWPB]
//   [585216,851456)  : gthw     u32[NBB*TROWS*GTW]  packed fp16 NEGATED px corners (inf-padded)

// ---------------- phase 0: prep ----------------
__global__ __launch_bounds__(64) void prep_kernel(const float* __restrict__ tgt,
                                                  float* __restrict__ gts_neg,
                                                  unsigned* __restrict__ gthw,
                                                  int* __restrict__ nvalid){
  int b = blockIdx.x;
  int t = threadIdx.x;
  const float* trow = tgt + (size_t)b*NTT*LL;
  float v1 = (t < NTT) ? trow[t*LL + 1] : 0.0f;
  unsigned long long mk = __ballot(t < NTT && v1 != 0.0f);
  int nv = __ffsll(~mk) - 1;                 // cumprod-valid prefix length
  if (t == 0) nvalid[b] = nv;
  // fp32 exact table (50 rows)
  for (int idx = t; idx < NTT*GTS; idx += 64){
    int tt = idx / GTS;
    int c  = idx - tt*GTS;
    float v;
    if (c == 9 || c == 19)      v = BIGV;
    else if (c < 9)             v = -(trow[tt*LL + 1 + 2*c] * 640.0f);
    else                        v = -(trow[tt*LL + 2 + 2*(c-10)] * 480.0f);
    gts_neg[(size_t)b*NTT*GTS + idx] = v;
  }
  // packed fp16 table (52 rows, rows >= nv are all +inf)
  if (t < TROWS){
    unsigned w[GTW];
    if (t < nv){
      const float* tr = trow + t*LL;
      float xs[KK], ys[KK];
#pragma unroll
      for (int k = 0; k < KK; ++k){
        xs[k] = -(tr[1+2*k] * 640.0f);
        ys[k] = -(tr[2+2*k] * 480.0f);
      }
#pragma unroll
      for (int p = 0; p < 4; ++p){
        w[p]   = (unsigned)f2h_bits(xs[2*p]) | ((unsigned)f2h_bits(xs[2*p+1]) << 16);
        w[5+p] = (unsigned)f2h_bits(ys[2*p]) | ((unsigned)f2h_bits(ys[2*p+1]) << 16);
      }
      w[4] = (unsigned)f2h_bits(xs[8]) | (INFH << 16);
      w[9] = (unsigned)f2h_bits(ys[8]) | (INFH << 16);
    } else {
#pragma unroll
      for (int p = 0; p < GTW; ++p) w[p] = INFH2;
    }
    unsigned* dst = gthw + ((size_t)b*TROWS + t)*GTW;
#pragma unroll
    for (int p = 0; p < GTW; ++p) dst[p] = w[p];
  }
}

// ---------------- phase A: chord-bound fp16 cull; exact path ~never fires ----------------
__global__ __launch_bounds__(128) void region_confmask_kernel(
    const float* __restrict__ outp, const unsigned* __restrict__ gthw,
    const float* __restrict__ gts_neg, unsigned int* __restrict__ maskw,
    double* __restrict__ partials){
  int b = blockIdx.y;
  int tid = threadIdx.x;
  int c0 = blockIdx.x * 128 + tid;          // [0,1792)
  int c1 = c0 + HALFSPLIT;                  // [1792,3584)
  bool ok1 = (c1 < NANCHT);

  // prologue: packed fp16 pred corners only (fp32 recomputed in cold exact path)
  int Pxw0[5], Pyw0[5], Pxw1[5], Pyw1[5];
  float cf0, cf1 = 0.0f;
  {
    int a = c0 / NPIX, rem = c0 - a*NPIX;
    int j = rem / NWW, i = rem - j*NWW;
    const float* base = outp + (((size_t)b*NANC + a)*CHC)*NPIX + rem;
    unsigned short hx[10], hy[10];
#pragma unroll
    for (int k = 0; k < KK; ++k){
      float rx = base[(2*k)*NPIX], ry = base[(2*k+1)*NPIX];
      if (k == 0){ rx = sigmoidf_(rx); ry = sigmoidf_(ry); }
      hx[k] = f2h_bits((rx + (float)i)*SXW);
      hy[k] = f2h_bits((ry + (float)j)*SYH);
    }
    hx[9] = 0; hy[9] = 0;
#pragma unroll
    for (int p = 0; p < 5; ++p){
      Pxw0[p] = (int)((unsigned)hx[2*p] | ((unsigned)hx[2*p+1] << 16));
      Pyw0[p] = (int)((unsigned)hy[2*p] | ((unsigned)hy[2*p+1] << 16));
    }
    cf0 = sigmoidf_(base[(2*KK)*NPIX]);
  }
  if (ok1){
    int a = c1 / NPIX, rem = c1 - a*NPIX;
    int j = rem / NWW, i = rem - j*NWW;
    const float* base = outp + (((size_t)b*NANC + a)*CHC)*NPIX + rem;
    unsigned short hx[10], hy[10];
#pragma unroll
    for (int k = 0; k < KK; ++k){
      float rx = base[(2*k)*NPIX], ry = base[(2*k+1)*NPIX];
      if (k == 0){ rx = sigmoidf_(rx); ry = sigmoidf_(ry); }
      hx[k] = f2h_bits((rx + (float)i)*SXW);
      hy[k] = f2h_bits((ry + (float)j)*SYH);
    }
    hx[9] = 0; hy[9] = 0;
#pragma unroll
    for (int p = 0; p < 5; ++p){
      Pxw1[p] = (int)((unsigned)hx[2*p] | ((unsigned)hx[2*p+1] << 16));
      Pyw1[p] = (int)((unsigned)hy[2*p] | ((unsigned)hy[2*p+1] << 16));
    }
    cf1 = sigmoidf_(base[(2*KK)*NPIX]);
  } else {
#pragma unroll
    for (int p = 0; p < 5; ++p){ Pxw1[p] = 0; Pyw1[p] = 0; }
  }

  // cull loop: 13 chunks x 4 targets; gt words via uniform s_load; chord-sum in pk-f16
  const int negC = (int)NEG6400W;
  const int zeroW = 0;
  const unsigned* gsrc = gthw + (size_t)b*TROWS*GTW;
  unsigned long long q0 = 0ull, q1 = 0ull;
#pragma unroll 1
  for (int c = 0; c < 13; ++c){
    int G[40];
#pragma unroll
    for (int w = 0; w < 40; ++w) G[w] = (int)gsrc[c*40 + w];   // uniform -> s_load
#pragma unroll
    for (int u = 0; u < 4; ++u){
      unsigned long long bit = 1ull << (c*4 + u);
      // cell 0: acc -= max(6400 - r2, 0) per corner (negative accumulation)
      {
        int acc = zeroW;
#pragma unroll
        for (int p = 0; p < 5; ++p){
          int dx = pk_add_sv(G[u*10+p],   Pxw0[p]);
          int dy = pk_add_sv(G[u*10+5+p], Pyw0[p]);
          int r2 = pk_mul_vv(dx, dx);
          r2 = pk_fma_vvv(dy, dy, r2);
          int um = pk_add_vv(r2, negC);     // r2 - 6400  (inf stays inf)
          um = pk_min_vv(um, zeroW);        // min(r2-6400, 0) = -max(6400-r2,0)
          acc = pk_add_vv(acc, um);
        }
        h2 ah = __builtin_bit_cast(h2, acc);
        float s = (float)ah[0] + (float)ah[1];
        if (s < CULL_FIRE_NEG) q0 |= bit;
      }
      // cell 1
      {
        int acc = zeroW;
#pragma unroll
        for (int p = 0; p < 5; ++p){
          int dx = pk_add_sv(G[u*10+p],   Pxw1[p]);
          int dy = pk_add_sv(G[u*10+5+p], Pyw1[p]);
          int r2 = pk_mul_vv(dx, dx);
          r2 = pk_fma_vvv(dy, dy, r2);
          int um = pk_add_vv(r2, negC);
          um = pk_min_vv(um, zeroW);
          acc = pk_add_vv(acc, um);
        }
        h2 ah = __builtin_bit_cast(h2, acc);
        float s = (float)ah[0] + (float)ah[1];
        if (s < CULL_FIRE_NEG) q1 |= bit;
      }
    }
  }
  if (!ok1) q1 = 0ull;

  // exact path (bit-exact R0 math). ~Never executed: cold recompute + global gt reads.
  int m0_0 = 1, m0_1 = 1;
  if (__any((q0 | q1) != 0ull)){
    const float* gbase = gts_neg + (size_t)b*NTT*GTS;
    if (q0){
      int a = c0 / NPIX, rem = c0 - a*NPIX;
      int j = rem / NWW, i = rem - j*NWW;
      const float* base = outp + (((size_t)b*NANC + a)*CHC)*NPIX + rem;
      float Pxf[KK], Pyf[KK];
#pragma unroll
      for (int k = 0; k < KK; ++k){
        float rx = base[(2*k)*NPIX], ry = base[(2*k+1)*NPIX];
        if (k == 0){ rx = sigmoidf_(rx); ry = sigmoidf_(ry); }
        Pxf[k] = (rx + (float)i)*SXW; Pyf[k] = (ry + (float)j)*SYH;
      }
      bool exc = false;
      while (q0){
        int t = __ffsll((long long)q0) - 1; q0 &= q0 - 1;
        const float* gg = gbase + t*GTS;
        float s = 0.0f;
#pragma unroll
        for (int k = 0; k < KK; ++k){
          float dx = Pxf[k] + gg[k], dy = Pyf[k] + gg[10+k];
          float d  = fast_sqrt(fmaf(dy, dy, dx*dx));
          float e  = fast_exp2(fmaf(d, -K2C, K1C));
          s += fmaxf(e, 1.0f);
        }
        exc |= (s > THRESH_S);
      }
      if (exc) m0_0 = 0;
    }
    if (q1){
      int a = c1 / NPIX, rem = c1 - a*NPIX;
      int j = rem / NWW, i = rem - j*NWW;
      const float* base = outp + (((size_t)b*NANC + a)*CHC)*NPIX + rem;
      float Pxf[KK], Pyf[KK];
#pragma unroll
      for (int k = 0; k < KK; ++k){
        float rx = base[(2*k)*NPIX], ry = base[(2*k+1)*NPIX];
        if (k == 0){ rx = sigmoidf_(rx); ry = sigmoidf_(ry); }
        Pxf[k] = (rx + (float)i)*SXW; Pyf[k] = (ry + (float)j)*SYH;
      }
      bool exc = false;
      while (q1){
        int t = __ffsll((long long)q1) - 1; q1 &= q1 - 1;
        const float* gg = gbase + t*GTS;
        float s = 0.0f;
#pragma unroll
        for (int k = 0; k < KK; ++k){
          float dx = Pxf[k] + gg[k], dy = Pyf[k] + gg[10+k];
          float d  = fast_sqrt(fmaf(dy, dy, dx*dx));
          float e  = fast_exp2(fmaf(d, -K2C, K1C));
          s += fmaxf(e, 1.0f);
        }
        exc |= (s > THRESH_S);
      }
      if (exc) m0_1 = 0;
    }
  }

  float contrib = (m0_0 ? 0.5f*cf0*cf0 : 0.0f) + ((ok1 && m0_1) ? 0.5f*cf1*cf1 : 0.0f);

  // bit-packed mask writes
  int lane = tid & 63;
  int wavebase0 = blockIdx.x * 128 + (tid & ~63);
  unsigned long long mb0 = __ballot(m0_0 != 0);
  if ((lane & 31) == 0){
    unsigned int w = (lane == 0) ? (unsigned int)mb0 : (unsigned int)(mb0 >> 32);
    maskw[(size_t)b*MWPB + (wavebase0 >> 5) + (lane >> 5)] = w;
  }
  unsigned long long mb1 = __ballot(m0_1 != 0);
  int wavebase1 = wavebase0 + HALFSPLIT;
  if ((lane & 31) == 0 && wavebase1 < NANCHT){
    unsigned int w = (lane == 0) ? (unsigned int)mb1 : (unsigned int)(mb1 >> 32);
    maskw[(size_t)b*MWPB + (wavebase1 >> 5) + (lane >> 5)] = w;
  }

  // block reduce -> one double partial per block
#pragma unroll
  for (int o = 32; o > 0; o >>= 1) contrib += __shfl_xor(contrib, o, 64);
  __shared__ float wsum[2];
  int wid = tid >> 6;
  if (lane == 0) wsum[wid] = contrib;
  __syncthreads();
  if (tid == 0)
    partials[b*NBLK + blockIdx.x] = (double)wsum[0] + (double)wsum[1];
}

// ---------------- phase B+C: scatter winners + small losses ----------------
__global__ __launch_bounds__(64) void scatter_loss_kernel(
    const float* __restrict__ outp, const float* __restrict__ tgt,
    const int* __restrict__ nvalid, const unsigned int* __restrict__ maskw,
    double* __restrict__ bc_part){
  int b = blockIdx.x;
  int t = threadIdx.x;
  __shared__ int keys[NTT];
  int nv = nvalid[b];
  bool valid = (t < nv);

  int key = -1, gi0 = 0, gj0 = 0, bn = 0;
  float txv[KK], tyv[KK];
  float conf_t = 0.0f, tcls = 0.0f;

  if (t < NTT){
    const float* trow = tgt + ((size_t)b*NTT + t)*LL;
    tcls = trow[0];
    float gx0 = trow[1]*(float)NWW;
    float gy0 = trow[2]*(float)NHH;
    gi0 = min(max((int)floorf(gx0), 0), NWW-1);
    gj0 = min(max((int)floorf(gy0), 0), NHH-1);
#pragma unroll
    for (int k = 0; k < KK; ++k){
      txv[k] = trow[1+2*k]*(float)NWW - (float)gi0;
      tyv[k] = trow[2+2*k]*(float)NHH - (float)gj0;
    }
    float gw = trow[LL-2]*(float)NWW, gh = trow[LL-1]*(float)NHH;
    float best = -1.0f;
    for (int a = 0; a < NANC; ++a){
      float aw = c_anch[2*a], ah = c_anch[2*a+1];
      float inter = fminf(aw, gw) * fminf(ah, gh);
      float iou = inter / (aw*ah + gw*gh - inter);
      if (iou > best){ best = iou; bn = a; }
    }
    key = bn*NPIX + gj0*NWW + gi0;
    keys[t] = key;

    long f = (long)b*NANCHT - NPIX + gj0*NWW + gi0;
    if (f < 0) f += NCELLT;
    int bb  = (int)(f / NANCHT);
    int rr  = (int)(f - (long)bb*NANCHT);
    int aa  = rr / NPIX;
    int rr2 = rr - aa*NPIX;
    int jj  = rr2 / NWW;
    int ii  = rr2 - jj*NWW;
    const float* pbase = outp + (((size_t)bb*NANC + aa)*CHC)*NPIX + rr2;
    float s = 0.0f;
#pragma unroll
    for (int k = 0; k < KK; ++k){
      float rx = pbase[(2*k)*NPIX], ry = pbase[(2*k+1)*NPIX];
      if (k == 0){ rx = sigmoidf_(rx); ry = sigmoidf_(ry); }
      float Pxx = (rx + (float)ii)*SXW, Pyy = (ry + (float)jj)*SYH;
      float dx = Pxx - trow[1+2*k]*640.0f;
      float dy = Pyy - trow[2+2*k]*480.0f;
      float d  = fast_sqrt(fmaf(dy, dy, dx*dx));
      float e  = fast_exp2(fmaf(d, -K2C, K1C));
      s += fmaxf(e, 1.0f);
    }
    conf_t = (s - 9.0f) * CONF_T_SCALE;
  }
  __syncthreads();

  bool winner = valid;
  if (valid){
    for (int u = t+1; u < nv; ++u) if (keys[u] == key){ winner = false; break; }
  }

  double lx = 0.0, ly = 0.0, lcls = 0.0, lcf = 0.0;
  if (winner){
    const float* cbase = outp + (((size_t)b*NANC + bn)*CHC)*NPIX + gj0*NWW + gi0;
    float sx = 0.0f, sy = 0.0f;
#pragma unroll
    for (int k = 0; k < KK; ++k){
      float rx = cbase[(2*k)*NPIX], ry = cbase[(2*k+1)*NPIX];
      if (k == 0){ rx = sigmoidf_(rx); ry = sigmoidf_(ry); }
      float dx = rx - txv[k], dy = ry - tyv[k];
      sx = fmaf(dx, dx, sx); sy = fmaf(dy, dy, sy);
    }
    lx = 0.5*(double)sx; ly = 0.5*(double)sy;

    float lg[NCLS], mx = -1e30f;
#pragma unroll
    for (int c = 0; c < NCLS; ++c){ lg[c] = cbase[(2*KK+1+c)*NPIX]; mx = fmaxf(mx, lg[c]); }
    float se = 0.0f;
#pragma unroll
    for (int c = 0; c < NCLS; ++c) se += fast_exp2((lg[c]-mx)*LOG2E_F);
    int label = min(max((int)tcls, 0), NCLS-1);
    lcls = (double)(mx + logf(se) - lg[label]);

    float cf = sigmoidf_(cbase[(2*KK)*NPIX]);
    int idx = bn*NPIX + gj0*NWW + gi0;
    int m0 = (maskw[(size_t)b*MWPB + (idx >> 5)] >> (idx & 31)) & 1;
    float dcf = cf - conf_t;
    lcf = 0.5*OBJ_W*(double)(dcf*dcf) - (m0 ? 0.5*(double)(cf*cf) : 0.0);
  }

#pragma unroll
  for (int o = 32; o > 0; o >>= 1){
    lx  += __shfl_xor(lx,  o, 64);
    ly  += __shfl_xor(ly,  o, 64);
    lcls+= __shfl_xor(lcls,o, 64);
    lcf += __shfl_xor(lcf, o, 64);
  }
  if (threadIdx.x == 0){
    double* bp = bc_part + (size_t)b*4;
    bp[0] = lx; bp[1] = ly; bp[2] = lcls; bp[3] = lcf;
  }
}

// ---------------- finalize ----------------
__global__ __launch_bounds__(256) void finalize_kernel(
    const double* __restrict__ bc_part, const double* __restrict__ partials,
    const int* __restrict__ epoch_p, float* __restrict__ outv){
  int tid = threadIdx.x;
  double vx=0, vy=0, vc=0, vf=0, vb=0;
  for (int i = tid; i < NBB; i += 256){
    vx += bc_part[4*i]; vy += bc_part[4*i+1];
    vc += bc_part[4*i+2]; vf += bc_part[4*i+3];
  }
  for (int i = tid; i < NBLK*NBB; i += 256) vb += partials[i];
#pragma unroll
  for (int o = 32; o > 0; o >>= 1){
    vx += __shfl_xor(vx, o, 64); vy += __shfl_xor(vy, o, 64);
    vc += __shfl_xor(vc, o, 64); vf += __shfl_xor(vf, o, 64);
    vb += __shfl_xor(vb, o, 64);
  }
  __shared__ double sm[5][4];
  int wid = tid >> 6, lane = tid & 63;
  if (lane == 0){ sm[0][wid]=vx; sm[1][wid]=vy; sm[2][wid]=vc; sm[3][wid]=vf; sm[4][wid]=vb; }
  __syncthreads();
  if (tid == 0){
    double fx=0, fy=0, fc=0, ff=0, fb=0;
    for (int w = 0; w < 4; ++w){ fx+=sm[0][w]; fy+=sm[1][w]; fc+=sm[2][w]; ff+=sm[3][w]; fb+=sm[4][w]; }
    double loss = fx + fy + fc;
    if (*epoch_p > EPOCH_PRETRAIN) loss += ff + fb;
    outv[0] = (float)loss;
  }
}

extern "C" void kernel_launch(void* const* d_in, const int* in_sizes, int n_in,
                              void* d_out, int out_size, void* d_ws, size_t ws_size,
                              hipStream_t stream){
  (void)in_sizes; (void)n_in; (void)out_size; (void)ws_size;
  const float* outp = (const float*)d_in[0];
  const float* tgt  = (const float*)d_in[1];
  const int*   ep   = (const int*)d_in[2];
  float* outv = (float*)d_out;
  char* ws = (char*)d_ws;

  double* bc_part   = (double*)(ws);                    // 4096 B
  double* partials  = (double*)(ws + 4096);             // 14336 B
  float*  gts_neg   = (float*) (ws + 18432);            // 512000 B
  int*    nvalid    = (int*)   (ws + 530432);           // 512 B
  unsigned int* maskw = (unsigned int*)(ws + 530944);   // 54272 B
  unsigned* gthw    = (unsigned*)(ws + 585216);         // 266240 B

  prep_kernel<<<dim3(NBB), dim3(64), 0, stream>>>(tgt, gts_neg, gthw, nvalid);
  region_confmask_kernel<<<dim3(NBLK, NBB), dim3(128), 0, stream>>>(outp, gthw, gts_neg, maskw, partials);
  scatter_loss_kernel<<<dim3(NBB), dim3(64), 0, stream>>>(outp, tgt, nvalid, maskw, bc_part);
  finalize_kernel<<<dim3(1), dim3(256), 0, stream>>>(bc_part, partials, ep, outv);
}

// Round 8
// 135.588 us; speedup vs baseline: 1.1056x; 1.0347x over previous
//
#include <hip/hip_runtime.h>
#include <math.h>

// ---------------- problem constants ----------------
#define KK     9
#define NCLS   13
#define NANC   5
#define NBB    128
#define NHH    26
#define NWW    26
#define NTT    50
#define LL     21
#define CHC    32
#define NPIX   676
#define NANCHT 3380
#define NCELLT 432640
#define GTS    20     // floats per target, fp32 exact-path table [x0..x8,BIG,y0..y8,BIG]
#define NPAIR  25     // target pairs
#define PWORDS 18     // u32 words per pair: X0..X8 (x_k of t0|t1), Y0..Y8
#define MWPB   106    // mask words per batch
#define NBLK   27     // confmask grid.x (27*128 = 3456 threads >= 3380 cells)

// derived float constants
#define LOG2E_F   1.4426950408889634f
#define K1C       2.8853900817779268f   // SHARP*log2e
#define K2C       0.036067376022224085f // K1C/TH
#define SXW       24.615384615384617f   // 640/26
#define SYH       18.461538461538463f   // 480/26
#define THRESH_S  43.500902934225507f   // 9 + SIL*9*(e^2-1)
#define CONF_T_SCALE 0.017390849194407297f
#define OBJ_W     5.0f
#define EPOCH_PRETRAIN 15
#define BIGV      6.0e18f
#define INFH      0x7C00u               // fp16 +inf
#define NEG6400W  0xEE40EE40u           // packed fp16 {-6400,-6400}
// chord-bound cull (per target half): fire iff sum_k min(r2_k-6400,0) < -31000
// true cut 34565 = 34.5049*6400/6.389; 3565 margin >> worst-case fp16 err ~2500
#define CULL_FIRE_NEG  -31000.0f

typedef _Float16 h2 __attribute__((ext_vector_type(2)));

static __device__ __forceinline__ float fast_exp2(float x){ return __builtin_amdgcn_exp2f(x); }
static __device__ __forceinline__ float fast_sqrt(float x){ return __builtin_amdgcn_sqrtf(x); }
static __device__ __forceinline__ float sigmoidf_(float x){
  return 1.0f/(1.0f + fast_exp2(-LOG2E_F*x));
}
// forced packed-fp16 ops (compiler scalarizes vector types; asm guarantees v_pk_*)
static __device__ __forceinline__ int pk_add_sv(int s, int v){
  int d; asm("v_pk_add_f16 %0, %1, %2" : "=v"(d) : "s"(s), "v"(v)); return d;
}
static __device__ __forceinline__ int pk_add_vv(int a, int b){
  int d; asm("v_pk_add_f16 %0, %1, %2" : "=v"(d) : "v"(a), "v"(b)); return d;
}
static __device__ __forceinline__ int pk_mul_vv(int a, int b){
  int d; asm("v_pk_mul_f16 %0, %1, %2" : "=v"(d) : "v"(a), "v"(b)); return d;
}
static __device__ __forceinline__ int pk_fma_vvv(int a, int b, int c){
  int d; asm("v_pk_fma_f16 %0, %1, %2, %3" : "=v"(d) : "v"(a), "v"(b), "v"(c)); return d;
}
static __device__ __forceinline__ int pk_min_vv(int a, int b){
  int d; asm("v_pk_min_f16 %0, %1, %2" : "=v"(d) : "v"(a), "v"(b)); return d;
}
static __device__ __forceinline__ unsigned short f2h_bits(float v){
  return __builtin_bit_cast(unsigned short, (_Float16)v);
}

__constant__ float c_anch[10] = {1.482f,2.2412f,2.0501f,3.1265f,2.3946f,4.6891f,
                                 3.1018f,3.991f,3.4879f,5.8851f};

// ws layout (bytes):
//   [0,4096)         : bc_part  double[NBB][4]
//   [4096,31744)     : partials double[NBLK*NBB]
//   [31744,543744)   : gts_neg  float[NBB*NTT*GTS]  fp32 NEGATED px corners
//   [543744,544256)  : nvalid   int[NBB]
//   [544256,598528)  : maskw    u32[NBB*MWPB]
//   [598528,828928)  : gtp      u32[NBB*NPAIR*PWORDS] target-pair-packed fp16 NEGATED corners

// ---------------- phase 0: prep ----------------
__global__ __launch_bounds__(64) void prep_kernel(const float* __restrict__ tgt,
                                                  float* __restrict__ gts_neg,
                                                  unsigned* __restrict__ gtp,
                                                  int* __restrict__ nvalid){
  int b = blockIdx.x;
  int t = threadIdx.x;
  const float* trow = tgt + (size_t)b*NTT*LL;
  float v1 = (t < NTT) ? trow[t*LL + 1] : 0.0f;
  unsigned long long mk = __ballot(t < NTT && v1 != 0.0f);
  int nv = __ffsll(~mk) - 1;                 // cumprod-valid prefix length
  if (t == 0) nvalid[b] = nv;
  // fp32 exact table (50 rows)
  for (int idx = t; idx < NTT*GTS; idx += 64){
    int tt = idx / GTS;
    int c  = idx - tt*GTS;
    float v;
    if (c == 9 || c == 19)      v = BIGV;
    else if (c < 9)             v = -(trow[tt*LL + 1 + 2*c] * 640.0f);
    else                        v = -(trow[tt*LL + 2 + 2*(c-10)] * 480.0f);
    gts_neg[(size_t)b*NTT*GTS + idx] = v;
  }
  // target-pair-packed fp16 table: word Xk = {x_k(2p), x_k(2p+1)}, invalid -> +inf
  if (t < NPAIR){
    int t0 = 2*t, t1 = 2*t + 1;
    unsigned w[PWORDS];
#pragma unroll
    for (int k = 0; k < KK; ++k){
      unsigned x0 = (t0 < nv) ? (unsigned)f2h_bits(-(trow[t0*LL+1+2*k]*640.0f)) : INFH;
      unsigned y0 = (t0 < nv) ? (unsigned)f2h_bits(-(trow[t0*LL+2+2*k]*480.0f)) : INFH;
      unsigned x1 = (t1 < nv) ? (unsigned)f2h_bits(-(trow[t1*LL+1+2*k]*640.0f)) : INFH;
      unsigned y1 = (t1 < nv) ? (unsigned)f2h_bits(-(trow[t1*LL+2+2*k]*480.0f)) : INFH;
      w[k]      = x0 | (x1 << 16);
      w[KK + k] = y0 | (y1 << 16);
    }
    unsigned* dst = gtp + ((size_t)b*NPAIR + t)*PWORDS;
#pragma unroll
    for (int p = 0; p < PWORDS; ++p) dst[p] = w[p];
  }
}

// ---------------- phase A: target-pair-packed chord cull, 1 cell/thread ----------------
__global__ __launch_bounds__(128) void region_confmask_kernel(
    const float* __restrict__ outp, const unsigned* __restrict__ gtp,
    const float* __restrict__ gts_neg, const int* __restrict__ nvalid,
    unsigned int* __restrict__ maskw, double* __restrict__ partials){
  int b = blockIdx.y;
  int tid = threadIdx.x;
  int cell = blockIdx.x * 128 + tid;
  bool active = (cell < NANCHT);
  int cc = active ? cell : (NANCHT - 1);

  // prologue: splat packed fp16 pred corners {h,h} per corner
  int Pxw[KK], Pyw[KK];
  float cf;
  int a = cc / NPIX, rem = cc - a*NPIX;
  int jj = rem / NWW, ii = rem - jj*NWW;
  const float* base = outp + (((size_t)b*NANC + a)*CHC)*NPIX + rem;
#pragma unroll
  for (int k = 0; k < KK; ++k){
    float rx = base[(2*k)*NPIX], ry = base[(2*k+1)*NPIX];
    if (k == 0){ rx = sigmoidf_(rx); ry = sigmoidf_(ry); }
    unsigned hx = f2h_bits((rx + (float)ii)*SXW);
    unsigned hy = f2h_bits((ry + (float)jj)*SYH);
    Pxw[k] = (int)(hx | (hx << 16));
    Pyw[k] = (int)(hy | (hy << 16));
  }
  cf = sigmoidf_(base[(2*KK)*NPIX]);

  // cull loop: 25 pairs; 18 uniform words via s_load; 7 pk ops/corner + 1 pk_min/pair
  const int negC = (int)NEG6400W;
  const unsigned* gp = gtp + (size_t)b*NPAIR*PWORDS;
  int M = 0;                                // running pk-min of per-target chord sums
#pragma unroll 2
  for (int p = 0; p < NPAIR; ++p){
    int G[PWORDS];
#pragma unroll
    for (int w = 0; w < PWORDS; ++w) G[w] = (int)gp[p*PWORDS + w];  // uniform -> s_load
    int acc = 0;
#pragma unroll
    for (int k = 0; k < KK; ++k){
      int dx = pk_add_sv(G[k],      Pxw[k]);
      int dy = pk_add_sv(G[KK + k], Pyw[k]);
      int r2 = pk_mul_vv(dx, dx);
      r2 = pk_fma_vvv(dy, dy, r2);
      int um = pk_add_vv(r2, negC);         // r2 - 6400 (inf stays inf)
      um = pk_min_vv(um, 0);                // -max(6400-r2,0)
      acc = pk_add_vv(acc, um);
    }
    M = pk_min_vv(M, acc);
  }

  h2 Mh = __builtin_bit_cast(h2, M);
  bool fire = ((float)Mh[0] < CULL_FIRE_NEG) | ((float)Mh[1] < CULL_FIRE_NEG);

  // exact path (bit-exact R0 math) — ~never fires; rescans all valid targets
  int m0 = 1;
  if (fire && active){
    float Pxf[KK], Pyf[KK];
#pragma unroll
    for (int k = 0; k < KK; ++k){
      float rx = base[(2*k)*NPIX], ry = base[(2*k+1)*NPIX];
      if (k == 0){ rx = sigmoidf_(rx); ry = sigmoidf_(ry); }
      Pxf[k] = (rx + (float)ii)*SXW; Pyf[k] = (ry + (float)jj)*SYH;
    }
    int nv = nvalid[b];
    const float* gbase = gts_neg + (size_t)b*NTT*GTS;
    bool exc = false;
    for (int t = 0; t < nv; ++t){
      const float* gg = gbase + t*GTS;
      float s = 0.0f;
#pragma unroll
      for (int k = 0; k < KK; ++k){
        float dx = Pxf[k] + gg[k], dy = Pyf[k] + gg[10+k];
        float d  = fast_sqrt(fmaf(dy, dy, dx*dx));
        float e  = fast_exp2(fmaf(d, -K2C, K1C));
        s += fmaxf(e, 1.0f);
      }
      exc |= (s > THRESH_S);
    }
    if (exc) m0 = 0;
  }

  float contrib = (active && m0) ? 0.5f*cf*cf : 0.0f;

  // bit-packed mask write: one ballot per wave, two u32 stores
  int lane = tid & 63;
  int wavebase = blockIdx.x * 128 + (tid & ~63);
  unsigned long long mb = __ballot(m0 != 0);
  if ((lane & 31) == 0 && wavebase < NANCHT){
    unsigned int w = (lane == 0) ? (unsigned int)mb : (unsigned int)(mb >> 32);
    maskw[(size_t)b*MWPB + (wavebase >> 5) + (lane >> 5)] = w;
  }

  // block reduce -> one double partial per block
#pragma unroll
  for (int o = 32; o > 0; o >>= 1) contrib += __shfl_xor(contrib, o, 64);
  __shared__ float wsum[2];
  int wid = tid >> 6;
  if (lane == 0) wsum[wid] = contrib;
  __syncthreads();
  if (tid == 0)
    partials[b*NBLK + blockIdx.x] = (double)wsum[0] + (double)wsum[1];
}

// ---------------- phase B+C: scatter winners + small losses ----------------
__global__ __launch_bounds__(64) void scatter_loss_kernel(
    const float* __restrict__ outp, const float* __restrict__ tgt,
    const int* __restrict__ nvalid, const unsigned int* __restrict__ maskw,
    double* __restrict__ bc_part){
  int b = blockIdx.x;
  int t = threadIdx.x;
  __shared__ int keys[NTT];
  int nv = nvalid[b];
  bool valid = (t < nv);

  int key = -1, gi0 = 0, gj0 = 0, bn = 0;
  float txv[KK], tyv[KK];
  float conf_t = 0.0f, tcls = 0.0f;

  if (t < NTT){
    const float* trow = tgt + ((size_t)b*NTT + t)*LL;
    tcls = trow[0];
    float gx0 = trow[1]*(float)NWW;
    float gy0 = trow[2]*(float)NHH;
    gi0 = min(max((int)floorf(gx0), 0), NWW-1);
    gj0 = min(max((int)floorf(gy0), 0), NHH-1);
#pragma unroll
    for (int k = 0; k < KK; ++k){
      txv[k] = trow[1+2*k]*(float)NWW - (float)gi0;
      tyv[k] = trow[2+2*k]*(float)NHH - (float)gj0;
    }
    float gw = trow[LL-2]*(float)NWW, gh = trow[LL-1]*(float)NHH;
    float best = -1.0f;
    for (int a = 0; a < NANC; ++a){
      float aw = c_anch[2*a], ah = c_anch[2*a+1];
      float inter = fminf(aw, gw) * fminf(ah, gh);
      float iou = inter / (aw*ah + gw*gh - inter);
      if (iou > best){ best = iou; bn = a; }
    }
    key = bn*NPIX + gj0*NWW + gi0;
    keys[t] = key;

    long f = (long)b*NANCHT - NPIX + gj0*NWW + gi0;
    if (f < 0) f += NCELLT;
    int bb  = (int)(f / NANCHT);
    int rr  = (int)(f - (long)bb*NANCHT);
    int aa  = rr / NPIX;
    int rr2 = rr - aa*NPIX;
    int jj  = rr2 / NWW;
    int ii  = rr2 - jj*NWW;
    const float* pbase = outp + (((size_t)bb*NANC + aa)*CHC)*NPIX + rr2;
    float s = 0.0f;
#pragma unroll
    for (int k = 0; k < KK; ++k){
      float rx = pbase[(2*k)*NPIX], ry = pbase[(2*k+1)*NPIX];
      if (k == 0){ rx = sigmoidf_(rx); ry = sigmoidf_(ry); }
      float Pxx = (rx + (float)ii)*SXW, Pyy = (ry + (float)jj)*SYH;
      float dx = Pxx - trow[1+2*k]*640.0f;
      float dy = Pyy - trow[2+2*k]*480.0f;
      float d  = fast_sqrt(fmaf(dy, dy, dx*dx));
      float e  = fast_exp2(fmaf(d, -K2C, K1C));
      s += fmaxf(e, 1.0f);
    }
    conf_t = (s - 9.0f) * CONF_T_SCALE;
  }
  __syncthreads();

  bool winner = valid;
  if (valid){
    for (int u = t+1; u < nv; ++u) if (keys[u] == key){ winner = false; break; }
  }

  double lx = 0.0, ly = 0.0, lcls = 0.0, lcf = 0.0;
  if (winner){
    const float* cbase = outp + (((size_t)b*NANC + bn)*CHC)*NPIX + gj0*NWW + gi0;
    float sx = 0.0f, sy = 0.0f;
#pragma unroll
    for (int k = 0; k < KK; ++k){
      float rx = cbase[(2*k)*NPIX], ry = cbase[(2*k+1)*NPIX];
      if (k == 0){ rx = sigmoidf_(rx); ry = sigmoidf_(ry); }
      float dx = rx - txv[k], dy = ry - tyv[k];
      sx = fmaf(dx, dx, sx); sy = fmaf(dy, dy, sy);
    }
    lx = 0.5*(double)sx; ly = 0.5*(double)sy;

    float lg[NCLS], mx = -1e30f;
#pragma unroll
    for (int c = 0; c < NCLS; ++c){ lg[c] = cbase[(2*KK+1+c)*NPIX]; mx = fmaxf(mx, lg[c]); }
    float se = 0.0f;
#pragma unroll
    for (int c = 0; c < NCLS; ++c) se += fast_exp2((lg[c]-mx)*LOG2E_F);
    int label = min(max((int)tcls, 0), NCLS-1);
    lcls = (double)(mx + logf(se) - lg[label]);

    float cf = sigmoidf_(cbase[(2*KK)*NPIX]);
    int idx = bn*NPIX + gj0*NWW + gi0;
    int m0 = (maskw[(size_t)b*MWPB + (idx >> 5)] >> (idx & 31)) & 1;
    float dcf = cf - conf_t;
    lcf = 0.5*OBJ_W*(double)(dcf*dcf) - (m0 ? 0.5*(double)(cf*cf) : 0.0);
  }

#pragma unroll
  for (int o = 32; o > 0; o >>= 1){
    lx  += __shfl_xor(lx,  o, 64);
    ly  += __shfl_xor(ly,  o, 64);
    lcls+= __shfl_xor(lcls,o, 64);
    lcf += __shfl_xor(lcf, o, 64);
  }
  if (threadIdx.x == 0){
    double* bp = bc_part + (size_t)b*4;
    bp[0] = lx; bp[1] = ly; bp[2] = lcls; bp[3] = lcf;
  }
}

// ---------------- finalize ----------------
__global__ __launch_bounds__(256) void finalize_kernel(
    const double* __restrict__ bc_part, const double* __restrict__ partials,
    const int* __restrict__ epoch_p, float* __restrict__ outv){
  int tid = threadIdx.x;
  double vx=0, vy=0, vc=0, vf=0, vb=0;
  for (int i = tid; i < NBB; i += 256){
    vx += bc_part[4*i]; vy += bc_part[4*i+1];
    vc += bc_part[4*i+2]; vf += bc_part[4*i+3];
  }
  for (int i = tid; i < NBLK*NBB; i += 256) vb += partials[i];
#pragma unroll
  for (int o = 32; o > 0; o >>= 1){
    vx += __shfl_xor(vx, o, 64); vy += __shfl_xor(vy, o, 64);
    vc += __shfl_xor(vc, o, 64); vf += __shfl_xor(vf, o, 64);
    vb += __shfl_xor(vb, o, 64);
  }
  __shared__ double sm[5][4];
  int wid = tid >> 6, lane = tid & 63;
  if (lane == 0){ sm[0][wid]=vx; sm[1][wid]=vy; sm[2][wid]=vc; sm[3][wid]=vf; sm[4][wid]=vb; }
  __syncthreads();
  if (tid == 0){
    double fx=0, fy=0, fc=0, ff=0, fb=0;
    for (int w = 0; w < 4; ++w){ fx+=sm[0][w]; fy+=sm[1][w]; fc+=sm[2][w]; ff+=sm[3][w]; fb+=sm[4][w]; }
    double loss = fx + fy + fc;
    if (*epoch_p > EPOCH_PRETRAIN) loss += ff + fb;
    outv[0] = (float)loss;
  }
}

extern "C" void kernel_launch(void* const* d_in, const int* in_sizes, int n_in,
                              void* d_out, int out_size, void* d_ws, size_t ws_size,
                              hipStream_t stream){
  (void)in_sizes; (void)n_in; (void)out_size; (void)ws_size;
  const float* outp = (const float*)d_in[0];
  const float* tgt  = (const float*)d_in[1];
  const int*   ep   = (const int*)d_in[2];
  float* outv = (float*)d_out;
  char* ws = (char*)d_ws;

  double* bc_part   = (double*)(ws);                    // 4096 B
  double* partials  = (double*)(ws + 4096);             // 27648 B
  float*  gts_neg   = (float*) (ws + 31744);            // 512000 B
  int*    nvalid    = (int*)   (ws + 543744);           // 512 B
  unsigned int* maskw = (unsigned int*)(ws + 544256);   // 54272 B
  unsigned* gtp     = (unsigned*)(ws + 598528);         // 230400 B

  prep_kernel<<<dim3(NBB), dim3(64), 0, stream>>>(tgt, gts_neg, gtp, nvalid);
  region_confmask_kernel<<<dim3(NBLK, NBB), dim3(128), 0, stream>>>(outp, gtp, gts_neg, nvalid, maskw, partials);
  scatter_loss_kernel<<<dim3(NBB), dim3(64), 0, stream>>>(outp, tgt, nvalid, maskw, bc_part);
  finalize_kernel<<<dim3(1), dim3(256), 0, stream>>>(bc_part, partials, ep, outv);
}